// Round 4
// baseline (110.713 us; speedup 1.0000x reference)
//
#include <hip/hip_runtime.h>

#define R 192
#define BATCH 1024
#define NTILE 24              // 24 i-tiles of 8 rooms
#define NSTRIPE 8
#define K2_BLOCKS (NSTRIPE * NTILE * 4)   // 768

// ws layout:
//   ws[0] = overlap accumulator (float, zeroed by K1 blk 114)
//   ws[1] = adjacency accumulator
//   ws[2] = ticket counter (u32, zeroed by K1 blk 114)
//   ws[4 .. 4+192)          = K1 transpose per-block MSE partials (96 x {mp,ms})
//   byte 1024               = maskT[24][192] bytes, bit k = adj(8t+k, j)>0 && j>8t+k
//   byte 8192               = roomA[r][b] float4 = (x, y, x+w, y+h)   (3 MB)
//   byte 8192 + 3<<20       = roomC[r][b] float2 = (cx, cy)           (1.5 MB)
#define MASKT_OFF_B 1024
#define ROOMA_OFF_B 8192
#define ROOMC_OFF_B (8192 + (3 << 20))

__global__ __launch_bounds__(256) void prep_kernel(
    const float* __restrict__ pos, const float* __restrict__ siz,
    const float* __restrict__ tpos, const float* __restrict__ tsiz,
    const int* __restrict__ adj, float* __restrict__ ws)
{
    const int blk = blockIdx.x;
    const int tid = threadIdx.x;

    if (blk < 96) {
        // ---- transpose + MSE ----
        __shared__ float wsum[4][2];
        float4* roomA = (float4*)((char*)ws + ROOMA_OFF_B);
        float2* roomC = (float2*)((char*)ws + ROOMC_OFF_B);
        const int bg = blk & 3;
        const int rt = blk >> 2;           // 0..23
        const int b  = bg * 256 + tid;

        const float2* pb  = (const float2*)pos  + (size_t)b * R;
        const float2* sb  = (const float2*)siz  + (size_t)b * R;
        const float2* tpb = (const float2*)tpos + (size_t)b * R;
        const float2* tsb = (const float2*)tsiz + (size_t)b * R;

        float mp = 0.0f, ms = 0.0f;
        #pragma unroll
        for (int k = 0; k < 8; ++k) {
            const int r = rt * 8 + k;
            float2 p  = pb[r];
            float2 s  = sb[r];
            float2 tp = tpb[r];
            float2 ts = tsb[r];
            float dpx = p.x - tp.x, dpy = p.y - tp.y;
            float dsx = s.x - ts.x, dsy = s.y - ts.y;
            mp += dpx * dpx + dpy * dpy;
            ms += dsx * dsx + dsy * dsy;
            roomA[r * BATCH + b] = make_float4(p.x, p.y, p.x + s.x, p.y + s.y);
            roomC[r * BATCH + b] = make_float2(fmaf(0.5f, s.x, p.x), fmaf(0.5f, s.y, p.y));
        }
        for (int off = 32; off > 0; off >>= 1) {
            mp += __shfl_down(mp, off);
            ms += __shfl_down(ms, off);
        }
        const int wid = tid >> 6, lane = tid & 63;
        if (lane == 0) { wsum[wid][0] = mp; wsum[wid][1] = ms; }
        __syncthreads();
        if (tid == 0) {
            ws[4 + blk * 2]     = wsum[0][0] + wsum[1][0] + wsum[2][0] + wsum[3][0];
            ws[4 + blk * 2 + 1] = wsum[0][1] + wsum[1][1] + wsum[2][1] + wsum[3][1];
        }
    } else if (blk < 114) {
        // ---- mask byte table ----
        unsigned char* maskT = (unsigned char*)ws + MASKT_OFF_B;
        const int e = (blk - 96) * 256 + tid;       // 0 .. 4607
        if (e < NTILE * R) {
            const int t = e / R;
            const int j = e - t * R;
            unsigned int m = 0;
            #pragma unroll
            for (int k = 0; k < 8; ++k) {
                const int i = 8 * t + k;
                m |= ((adj[i * R + j] > 0) && (j > i)) ? (1u << k) : 0u;
            }
            maskT[e] = (unsigned char)m;
        }
    } else {
        // ---- zero accumulators + ticket ----
        if (tid < 4) ws[tid] = 0.0f;
    }
}

__global__ __launch_bounds__(256) void pairs_kernel(float* __restrict__ ws,
                                                    float* __restrict__ out)
{
    __shared__ float wsum[4][2];
    __shared__ int is_last;

    const float4* __restrict__ roomA = (const float4*)((const char*)ws + ROOMA_OFF_B);
    const float2* __restrict__ roomC = (const float2*)((const char*)ws + ROOMC_OFF_B);
    const unsigned char* __restrict__ maskT = (const unsigned char*)ws + MASKT_OFF_B;

    const int s   = blockIdx.x;           // 0..7  j-stripe
    const int t   = blockIdx.y;           // 0..23 i-tile
    const int bg  = blockIdx.z;           // 0..3  batch group
    const int tid = threadIdx.x;
    const int b   = bg * 256 + tid;
    const int i0  = 8 * t;

    // i-side operands in registers
    float4 A[8];
    float2 C[8];
    #pragma unroll
    for (int k = 0; k < 8; ++k) {
        A[k] = roomA[(i0 + k) * BATCH + b];
        C[k] = roomC[(i0 + k) * BATCH + b];
    }

    float ov = 0.0f, ad = 0.0f;

    for (int j = i0 + 8 + s; j < R; j += NSTRIPE) {
        const float4 rb = roomA[j * BATCH + b];
        const float2 rc = roomC[j * BATCH + b];
        const unsigned int m = __builtin_amdgcn_readfirstlane((unsigned int)maskT[t * R + j]);
        #pragma unroll
        for (int k = 0; k < 8; ++k) {
            float ow = fminf(A[k].z, rb.z) - fmaxf(A[k].x, rb.x);
            float oh = fminf(A[k].w, rb.w) - fmaxf(A[k].y, rb.y);
            ov = fmaf(fmaxf(ow, 0.0f), fmaxf(oh, 0.0f), ov);
            if (m & (1u << k)) {          // wave-uniform: s_cbranch skips sqrt
                float dx = C[k].x - rc.x;
                float dy = C[k].y - rc.y;
                ad += __builtin_amdgcn_sqrtf(fmaf(dx, dx, dy * dy));
            }
        }
    }

    if (s == 0) {
        // intra-tile triangle (28 pairs), operands all in registers
        #pragma unroll
        for (int k2 = 1; k2 < 8; ++k2) {
            const unsigned int m2 =
                __builtin_amdgcn_readfirstlane((unsigned int)maskT[t * R + i0 + k2]);
            #pragma unroll
            for (int k1 = 0; k1 < k2; ++k1) {
                float ow = fminf(A[k1].z, A[k2].z) - fmaxf(A[k1].x, A[k2].x);
                float oh = fminf(A[k1].w, A[k2].w) - fmaxf(A[k1].y, A[k2].y);
                ov = fmaf(fmaxf(ow, 0.0f), fmaxf(oh, 0.0f), ov);
                if (m2 & (1u << k1)) {
                    float dx = C[k1].x - C[k2].x;
                    float dy = C[k1].y - C[k2].y;
                    ad += __builtin_amdgcn_sqrtf(fmaf(dx, dx, dy * dy));
                }
            }
        }
    }

    // block reduction
    for (int off = 32; off > 0; off >>= 1) {
        ov += __shfl_down(ov, off);
        ad += __shfl_down(ad, off);
    }
    const int wid = tid >> 6, lane = tid & 63;
    if (lane == 0) { wsum[wid][0] = ov; wsum[wid][1] = ad; }
    __syncthreads();
    if (tid == 0) {
        float o = wsum[0][0] + wsum[1][0] + wsum[2][0] + wsum[3][0];
        float a = wsum[0][1] + wsum[1][1] + wsum[2][1] + wsum[3][1];
        atomicAdd(&ws[0], o);
        atomicAdd(&ws[1], a);
        __threadfence();
        unsigned int old = atomicAdd((unsigned int*)(ws + 2), 1u);
        is_last = (old == (unsigned int)(K2_BLOCKS - 1)) ? 1 : 0;
    }
    __syncthreads();

    if (is_last) {
        // fused finalize: sum K1's 96 MSE partial pairs (visible since K1 ended),
        // read ov/ad via coherent atomic RMW, emit the 5 outputs.
        float mp = (tid < 96) ? ws[4 + 2 * tid]     : 0.0f;
        float ms = (tid < 96) ? ws[4 + 2 * tid + 1] : 0.0f;
        for (int off = 32; off > 0; off >>= 1) {
            mp += __shfl_down(mp, off);
            ms += __shfl_down(ms, off);
        }
        if (lane == 0) { wsum[wid][0] = mp; wsum[wid][1] = ms; }
        __syncthreads();
        if (tid == 0) {
            float mseP = wsum[0][0] + wsum[1][0] + wsum[2][0] + wsum[3][0];
            float mseS = wsum[0][1] + wsum[1][1] + wsum[2][1] + wsum[3][1];
            float ovT  = atomicAdd(&ws[0], 0.0f);
            float adT  = atomicAdd(&ws[1], 0.0f);
            const float invN = 1.0f / (float)(BATCH * R * 2);
            const float invB = 1.0f / (float)BATCH;
            float pos_loss  = mseP * invN;
            float size_loss = mseS * invN;
            float overlap   = ovT * invB;
            float adjl      = adT * invB;
            out[0] = pos_loss + size_loss + 0.5f * overlap + 0.3f * adjl;
            out[1] = pos_loss;
            out[2] = size_loss;
            out[3] = overlap;
            out[4] = adjl;
        }
    }
}

extern "C" void kernel_launch(void* const* d_in, const int* in_sizes, int n_in,
                              void* d_out, int out_size, void* d_ws, size_t ws_size,
                              hipStream_t stream) {
    const float* pos  = (const float*)d_in[0];
    const float* siz  = (const float*)d_in[1];
    const float* tpos = (const float*)d_in[2];
    const float* tsiz = (const float*)d_in[3];
    const int*   adj  = (const int*)d_in[4];
    float* ws  = (float*)d_ws;
    float* out = (float*)d_out;

    hipLaunchKernelGGL(prep_kernel, dim3(115), dim3(256), 0, stream,
                       pos, siz, tpos, tsiz, adj, ws);
    hipLaunchKernelGGL(pairs_kernel, dim3(NSTRIPE, NTILE, 4), dim3(256), 0, stream,
                       ws, out);
}